// Round 7
// baseline (373.072 us; speedup 1.0000x reference)
//
#include <hip/hip_runtime.h>
#include <hip/hip_cooperative_groups.h>
namespace cg = cooperative_groups;

constexpr int TPB   = 256;    // generic block
constexpr int NMAX  = 16384;  // fast-path cap (node ids fit 20 bits, rloc 6 bits)
constexpr int CHUNK = 2048;   // edges per p1 block/phase
constexpr int GBMAX = 1024;   // fast-path cap on p1 grid
constexpr int STGN  = 12288;  // p2 LDS staging entries (96 KB)
constexpr int RCAP  = 12;     // register-held entries/thread in p2
constexpr int MGB   = 256;    // mega-kernel grid (1 block/CU)

// ===================== cooperative mega-kernel (fast path) =====================
// All six phases in one kernel; 5 grid.sync()s replace 5 kernel-launch gaps.
// LDS: one 98 KB union reused per phase -> 1 block/CU, 16 waves.

union SMemU {
    struct { int cnt[256]; int curs[256]; int sc[256]; int2 stg[2 * CHUNK]; } p1; // 35 KB
    struct { int sco[256]; int ncnt[64]; int nstart[64]; int ncur[64];
             float wsum[64]; int2 stg[STGN]; } p2;                                // 98 KB
    float wl[64 * 64];                                                            // 16 KB
    float w2l[64 * 16];                                                           // 4 KB
};

__global__ __launch_bounds__(1024) void k_mega(
    const float* __restrict__ x, const float* __restrict__ W1,
    const float* __restrict__ b1, const float* __restrict__ W2,
    const float* __restrict__ b2, const float* __restrict__ ew,
    const int* __restrict__ ei,
    int N, int E, int M, int rsh, int NBe, int GB,
    float* __restrict__ dis, int* __restrict__ rowptr, int2* __restrict__ ent,
    int* __restrict__ bstartT, int* __restrict__ bcntT, int* __restrict__ btot,
    int2* __restrict__ tmp, float* __restrict__ Z1, float* __restrict__ Z2,
    float* __restrict__ out)
{
    cg::grid_group grid = cg::this_grid();
    __shared__ SMemU sm;
    const int tid = threadIdx.x;
    const long long* entq = (const long long*)ent;

    // ================= phase 1: p1 (edge partition into bucket runs) =================
    for (int b = blockIdx.x; b < GB; b += MGB) {
        int e0 = b * CHUNK;
        int e1 = min(E, e0 + CHUNK);
        if (tid < NBe) sm.p1.cnt[tid] = 0;
        __syncthreads();
        int ea = e0 + tid, ebg = e0 + 1024 + tid;
        int r0 = 0, c0 = 0, r1 = 0, c1 = 0, w0 = 0, w1 = 0;
        bool va = ea < e1, vb = ebg < e1;
        if (va) { r0 = ei[ea];  c0 = ei[E + ea];  w0 = __float_as_int(0.5f * ew[ea]); }
        if (vb) { r1 = ei[ebg]; c1 = ei[E + ebg]; w1 = __float_as_int(0.5f * ew[ebg]); }
        if (va) { atomicAdd(&sm.p1.cnt[r0 >> rsh], 1); atomicAdd(&sm.p1.cnt[c0 >> rsh], 1); }
        if (vb) { atomicAdd(&sm.p1.cnt[r1 >> rsh], 1); atomicAdd(&sm.p1.cnt[c1 >> rsh], 1); }
        __syncthreads();
        int myc = (tid < NBe) ? sm.p1.cnt[tid] : 0;
        if (tid < NBe) sm.p1.sc[tid] = myc;
        __syncthreads();
        for (int off = 1; off < NBe; off <<= 1) {
            int v = 0;
            if (tid < NBe && tid >= off) v = sm.p1.sc[tid - off];
            __syncthreads();
            if (tid < NBe) sm.p1.sc[tid] += v;
            __syncthreads();
        }
        if (tid < NBe) {
            int excl = sm.p1.sc[tid] - myc;
            sm.p1.curs[tid] = excl;
            bstartT[tid * GB + b] = 2 * e0 + excl;   // transposed
            bcntT[tid * GB + b] = myc;
        }
        __syncthreads();
        int mask = (1 << rsh) - 1;
        if (va) {
            int p = atomicAdd(&sm.p1.curs[r0 >> rsh], 1);
            sm.p1.stg[p] = make_int2(((r0 & mask) << 20) | c0, w0);
            p = atomicAdd(&sm.p1.curs[c0 >> rsh], 1);
            sm.p1.stg[p] = make_int2(((c0 & mask) << 20) | r0, w0);
        }
        if (vb) {
            int p = atomicAdd(&sm.p1.curs[r1 >> rsh], 1);
            sm.p1.stg[p] = make_int2(((r1 & mask) << 20) | c1, w1);
            p = atomicAdd(&sm.p1.curs[c1 >> rsh], 1);
            sm.p1.stg[p] = make_int2(((c1 & mask) << 20) | r1, w1);
        }
        __syncthreads();
        int tot = 2 * (e1 - e0);
        for (int i = tid; i < tot; i += 1024) tmp[2 * e0 + i] = sm.p1.stg[i];
        __syncthreads();   // LDS reused next chunk iteration
    }
    grid.sync();

    // ================= phase 2: colsum -> btot[k] =================
    if (blockIdx.x < NBe) {
        int k = blockIdx.x;
        int s = 0;
        for (int bb = tid; bb < GB; bb += 1024) s += bcntT[k * GB + bb];
        #pragma unroll
        for (int off = 32; off; off >>= 1) s += __shfl_down(s, off, 64);
        if ((tid & 63) == 0) sm.p1.cnt[tid >> 6] = s;
        __syncthreads();
        if (tid == 0) {
            int t = 0;
            #pragma unroll
            for (int w = 0; w < 16; ++w) t += sm.p1.cnt[w];
            btot[k] = t;
        }
    }
    grid.sync();

    // ================= phase 3: p2 (bucket local sort -> CSR + dis) =================
    if (blockIdx.x < NBe) {
        int k = blockIdx.x;
        int RN = 1 << rsh;
        int n0 = k << rsh;
        const int base = k * GB;
        int grp = tid >> 2, sub = tid & 3;
        int s0 = 0, l0 = 0;
        if (grp < GB) { s0 = bstartT[base + grp]; l0 = bcntT[base + grp]; }
        int2 r[RCAP];
        #pragma unroll
        for (int u = 0; u < RCAP; ++u) {
            int idx = sub + 4 * u;
            if (idx < l0) r[u] = tmp[s0 + idx];
        }
        int bt = (tid < NBe) ? btot[tid] : 0;
        if (tid < 256) sm.p2.sco[tid] = bt;
        if (tid < RN) { sm.p2.ncnt[tid] = 0; sm.p2.wsum[tid] = 0.f; }
        __syncthreads();
        for (int off = 1; off < 256; off <<= 1) {
            int v = 0;
            if (tid < 256 && tid >= off) v = sm.p2.sco[tid - off];
            __syncthreads();
            if (tid < 256) sm.p2.sco[tid] += v;
            __syncthreads();
        }
        int eb = sm.p2.sco[k] - btot[k];
        int tot = btot[k];
        bool useStg = (tot <= STGN);
        #pragma unroll
        for (int u = 0; u < RCAP; ++u)
            if (sub + 4 * u < l0) atomicAdd(&sm.p2.ncnt[r[u].x >> 20], 1);
        for (int idx = sub + 4 * RCAP; idx < l0; idx += 4)
            atomicAdd(&sm.p2.ncnt[tmp[s0 + idx].x >> 20], 1);
        for (int b = grp + 256; b < GB; b += 256) {
            int s = bstartT[base + b], l = bcntT[base + b];
            for (int idx = sub; idx < l; idx += 4)
                atomicAdd(&sm.p2.ncnt[tmp[s + idx].x >> 20], 1);
        }
        __syncthreads();
        int myc = (tid < RN) ? sm.p2.ncnt[tid] : 0;
        if (tid < RN) sm.p2.nstart[tid] = myc;
        __syncthreads();
        for (int off = 1; off < RN; off <<= 1) {
            int v = 0;
            if (tid < RN && tid >= off) v = sm.p2.nstart[tid - off];
            __syncthreads();
            if (tid < RN) sm.p2.nstart[tid] += v;
            __syncthreads();
        }
        if (tid < RN) { sm.p2.nstart[tid] -= myc; sm.p2.ncur[tid] = sm.p2.nstart[tid]; }
        __syncthreads();
        #pragma unroll
        for (int u = 0; u < RCAP; ++u)
            if (sub + 4 * u < l0) {
                int rl = r[u].x >> 20;
                int p = atomicAdd(&sm.p2.ncur[rl], 1);
                int2 v2 = make_int2(r[u].x & 0xFFFFF, r[u].y);
                if (useStg) sm.p2.stg[p] = v2; else ent[eb + p] = v2;
                atomicAdd(&sm.p2.wsum[rl], __int_as_float(r[u].y));
            }
        for (int idx = sub + 4 * RCAP; idx < l0; idx += 4) {
            int2 v = tmp[s0 + idx];
            int rl = v.x >> 20;
            int p = atomicAdd(&sm.p2.ncur[rl], 1);
            int2 v2 = make_int2(v.x & 0xFFFFF, v.y);
            if (useStg) sm.p2.stg[p] = v2; else ent[eb + p] = v2;
            atomicAdd(&sm.p2.wsum[rl], __int_as_float(v.y));
        }
        for (int b = grp + 256; b < GB; b += 256) {
            int s = bstartT[base + b], l = bcntT[base + b];
            for (int idx = sub; idx < l; idx += 4) {
                int2 v = tmp[s + idx];
                int rl = v.x >> 20;
                int p = atomicAdd(&sm.p2.ncur[rl], 1);
                int2 v2 = make_int2(v.x & 0xFFFFF, v.y);
                if (useStg) sm.p2.stg[p] = v2; else ent[eb + p] = v2;
                atomicAdd(&sm.p2.wsum[rl], __int_as_float(v.y));
            }
        }
        __syncthreads();
        if (useStg)
            for (int i = tid; i < tot; i += 1024) ent[eb + i] = sm.p2.stg[i];
        if (tid < RN && n0 + tid < N) {
            rowptr[n0 + tid] = eb + sm.p2.nstart[tid];
            dis[n0 + tid] = rsqrtf(1.f + sm.p2.wsum[tid]);
        }
        if (k == 0 && tid == 0) rowptr[N] = M;
    }
    grid.sync();

    // ================= phase 4: gemm1  Z1 = dis .* (X @ W1) =================
    for (int i = tid; i < 4096; i += 1024) sm.wl[i] = W1[i];
    __syncthreads();
    {
        int wid = tid >> 6, f = tid & 63;
        for (int row = blockIdx.x * 16 + wid; row < N; row += MGB * 16) {
            const float* xr = x + (size_t)row * 64;
            float s = 0.f;
            #pragma unroll
            for (int kk = 0; kk < 64; ++kk) s = fmaf(xr[kk], sm.wl[kk * 64 + f], s);
            Z1[(size_t)row * 64 + f] = dis[row] * s;
        }
    }
    grid.sync();

    // ================= phase 5: gather1 (+fused gemm2) =================
    if (tid < 1024) sm.w2l[tid & 1023] = W2[tid & 1023];   // 1024 floats, tid<1024 always
    __syncthreads();
    {
        int wid = tid >> 6, f = tid & 63;
        constexpr int UN = 16;
        for (int node = blockIdx.x * 16 + wid; node < N; node += MGB * 16) {
            int sj0 = __builtin_amdgcn_readfirstlane(rowptr[node]);
            int sj1 = __builtin_amdgcn_readfirstlane(rowptr[node + 1]);
            float acc = Z1[(size_t)node * 64 + f];
            float dn = dis[node];
            for (int jb = sj0; jb < sj1; jb += UN) {
                long long e[UN];
                #pragma unroll
                for (int u = 0; u < UN; ++u) e[u] = entq[jb + u];   // uniform s_load (pad-safe)
                float z[UN];
                #pragma unroll
                for (int u = 0; u < UN; ++u) {
                    int nn = (jb + u < sj1) ? (int)e[u] : 0;
                    z[u] = Z1[(size_t)nn * 64 + f];
                }
                #pragma unroll
                for (int u = 0; u < UN; ++u) {
                    float ww = (jb + u < sj1) ? __int_as_float((int)(e[u] >> 32)) : 0.0f;
                    acc = fmaf(ww, z[u], acc);
                }
            }
            float v = fmaf(dn, acc, b1[f]);
            v = v > 0.f ? v : 0.f;
            int q = f >> 4, j = f & 15;
            float s = 0.f;
            #pragma unroll
            for (int i = 0; i < 16; ++i) {
                float hk = __shfl(v, 16 * q + i);
                s = fmaf(hk, sm.w2l[(16 * q + i) * 16 + j], s);
            }
            s += __shfl_xor(s, 16);
            s += __shfl_xor(s, 32);
            if (f < 16) Z2[node * 16 + f] = dn * s;
        }
    }
    grid.sync();

    // ================= phase 6: gather2 -> out =================
    {
        int wid = tid >> 6;
        int lane = tid & 63;
        int g = lane >> 4, f = lane & 15;
        constexpr int UN = 4;
        for (int node = blockIdx.x * 16 + wid; node < N; node += MGB * 16) {
            int sj0 = __builtin_amdgcn_readfirstlane(rowptr[node]);
            int sj1 = __builtin_amdgcn_readfirstlane(rowptr[node + 1]);
            float acc = (g == 0) ? Z2[node * 16 + f] : 0.f;
            for (int jb = sj0; jb < sj1; jb += 4 * UN) {
                long long e[UN];
                #pragma unroll
                for (int u = 0; u < UN; ++u) e[u] = entq[jb + 4 * u + g];
                float z[UN], w[UN];
                #pragma unroll
                for (int u = 0; u < UN; ++u) {
                    bool ok = (jb + 4 * u + g) < sj1;
                    int nn = ok ? (int)e[u] : 0;
                    w[u] = ok ? __int_as_float((int)(e[u] >> 32)) : 0.f;
                    z[u] = Z2[nn * 16 + f];
                }
                #pragma unroll
                for (int u = 0; u < UN; ++u) acc = fmaf(w[u], z[u], acc);
            }
            acc += __shfl_xor(acc, 16);
            acc += __shfl_xor(acc, 32);
            if (lane < 16) out[node * 16 + f] = fmaf(dis[node], acc, b2[f]);
        }
    }
}

// ===================== standalone kernels (fallbacks) =====================

__global__ __launch_bounds__(1024) void k_p1(const int* __restrict__ ei,
    const float* __restrict__ ew, int E, int rsh, int NBe, int GB,
    int* __restrict__ bstartT, int* __restrict__ bcntT, int2* __restrict__ tmp) {
    __shared__ int cnt[256];
    __shared__ int curs[256];
    __shared__ int sc[256];
    __shared__ int2 stg[2 * CHUNK];
    int tid = threadIdx.x;
    int b = blockIdx.x;
    int e0 = b * CHUNK;
    int e1 = min(E, e0 + CHUNK);
    if (tid < NBe) cnt[tid] = 0;
    __syncthreads();
    int ea = e0 + tid, ebg = e0 + 1024 + tid;
    int r0 = 0, c0 = 0, r1 = 0, c1 = 0, w0 = 0, w1 = 0;
    bool va = ea < e1, vb = ebg < e1;
    if (va) { r0 = ei[ea];  c0 = ei[E + ea];  w0 = __float_as_int(0.5f * ew[ea]); }
    if (vb) { r1 = ei[ebg]; c1 = ei[E + ebg]; w1 = __float_as_int(0.5f * ew[ebg]); }
    if (va) { atomicAdd(&cnt[r0 >> rsh], 1); atomicAdd(&cnt[c0 >> rsh], 1); }
    if (vb) { atomicAdd(&cnt[r1 >> rsh], 1); atomicAdd(&cnt[c1 >> rsh], 1); }
    __syncthreads();
    int myc = (tid < NBe) ? cnt[tid] : 0;
    if (tid < NBe) sc[tid] = myc;
    __syncthreads();
    for (int off = 1; off < NBe; off <<= 1) {
        int v = 0;
        if (tid < NBe && tid >= off) v = sc[tid - off];
        __syncthreads();
        if (tid < NBe) sc[tid] += v;
        __syncthreads();
    }
    if (tid < NBe) {
        int excl = sc[tid] - myc;
        curs[tid] = excl;
        bstartT[tid * GB + b] = 2 * e0 + excl;
        bcntT[tid * GB + b] = myc;
    }
    __syncthreads();
    int mask = (1 << rsh) - 1;
    if (va) {
        int p = atomicAdd(&curs[r0 >> rsh], 1);
        stg[p] = make_int2(((r0 & mask) << 20) | c0, w0);
        p = atomicAdd(&curs[c0 >> rsh], 1);
        stg[p] = make_int2(((c0 & mask) << 20) | r0, w0);
    }
    if (vb) {
        int p = atomicAdd(&curs[r1 >> rsh], 1);
        stg[p] = make_int2(((r1 & mask) << 20) | c1, w1);
        p = atomicAdd(&curs[c1 >> rsh], 1);
        stg[p] = make_int2(((c1 & mask) << 20) | r1, w1);
    }
    __syncthreads();
    int tot = 2 * (e1 - e0);
    for (int i = tid; i < tot; i += 1024) tmp[2 * e0 + i] = stg[i];
}

__global__ void k_colsum(const int* __restrict__ bcntT, int GB,
                         int* __restrict__ btot) {
    __shared__ int red[TPB / 64];
    int k = blockIdx.x;
    int s = 0;
    for (int b = threadIdx.x; b < GB; b += TPB) s += bcntT[k * GB + b];
    #pragma unroll
    for (int off = 32; off; off >>= 1) s += __shfl_down(s, off, 64);
    int wv = threadIdx.x >> 6;
    if ((threadIdx.x & 63) == 0) red[wv] = s;
    __syncthreads();
    if (threadIdx.x == 0) {
        int t = 0;
        for (int w = 0; w < TPB / 64; ++w) t += red[w];
        btot[k] = t;
    }
}

__global__ __launch_bounds__(1024) void k_p2(const int2* __restrict__ tmp,
    const int* __restrict__ bstartT, const int* __restrict__ bcntT,
    const int* __restrict__ btot, int GB, int rsh, int N, int NBe, int M,
    int2* __restrict__ ent, int* __restrict__ rowptr, float* __restrict__ dis) {
    __shared__ int sco[256];
    __shared__ int ncnt[64];
    __shared__ int nstart[64];
    __shared__ int ncur[64];
    __shared__ float wsum[64];
    __shared__ int2 stg[STGN];
    int k = blockIdx.x;
    int tid = threadIdx.x;
    int RN = 1 << rsh;
    int n0 = k << rsh;
    const int base = k * GB;
    int grp = tid >> 2, sub = tid & 3;
    int s0 = 0, l0 = 0;
    if (grp < GB) { s0 = bstartT[base + grp]; l0 = bcntT[base + grp]; }
    int2 r[RCAP];
    #pragma unroll
    for (int u = 0; u < RCAP; ++u) {
        int idx = sub + 4 * u;
        if (idx < l0) r[u] = tmp[s0 + idx];
    }
    int bt = (tid < NBe) ? btot[tid] : 0;
    if (tid < 256) sco[tid] = bt;
    if (tid < RN) { ncnt[tid] = 0; wsum[tid] = 0.f; }
    __syncthreads();
    for (int off = 1; off < 256; off <<= 1) {
        int v = 0;
        if (tid < 256 && tid >= off) v = sco[tid - off];
        __syncthreads();
        if (tid < 256) sco[tid] += v;
        __syncthreads();
    }
    int eb = sco[k] - btot[k];
    int tot = btot[k];
    bool useStg = (tot <= STGN);
    #pragma unroll
    for (int u = 0; u < RCAP; ++u)
        if (sub + 4 * u < l0) atomicAdd(&ncnt[r[u].x >> 20], 1);
    for (int idx = sub + 4 * RCAP; idx < l0; idx += 4)
        atomicAdd(&ncnt[tmp[s0 + idx].x >> 20], 1);
    for (int b = grp + 256; b < GB; b += 256) {
        int s = bstartT[base + b], l = bcntT[base + b];
        for (int idx = sub; idx < l; idx += 4)
            atomicAdd(&ncnt[tmp[s + idx].x >> 20], 1);
    }
    __syncthreads();
    int myc = (tid < RN) ? ncnt[tid] : 0;
    if (tid < RN) nstart[tid] = myc;
    __syncthreads();
    for (int off = 1; off < RN; off <<= 1) {
        int v = 0;
        if (tid < RN && tid >= off) v = nstart[tid - off];
        __syncthreads();
        if (tid < RN) nstart[tid] += v;
        __syncthreads();
    }
    if (tid < RN) { nstart[tid] -= myc; ncur[tid] = nstart[tid]; }
    __syncthreads();
    #pragma unroll
    for (int u = 0; u < RCAP; ++u)
        if (sub + 4 * u < l0) {
            int rl = r[u].x >> 20;
            int p = atomicAdd(&ncur[rl], 1);
            int2 v2 = make_int2(r[u].x & 0xFFFFF, r[u].y);
            if (useStg) stg[p] = v2; else ent[eb + p] = v2;
            atomicAdd(&wsum[rl], __int_as_float(r[u].y));
        }
    for (int idx = sub + 4 * RCAP; idx < l0; idx += 4) {
        int2 v = tmp[s0 + idx];
        int rl = v.x >> 20;
        int p = atomicAdd(&ncur[rl], 1);
        int2 v2 = make_int2(v.x & 0xFFFFF, v.y);
        if (useStg) stg[p] = v2; else ent[eb + p] = v2;
        atomicAdd(&wsum[rl], __int_as_float(v.y));
    }
    for (int b = grp + 256; b < GB; b += 256) {
        int s = bstartT[base + b], l = bcntT[base + b];
        for (int idx = sub; idx < l; idx += 4) {
            int2 v = tmp[s + idx];
            int rl = v.x >> 20;
            int p = atomicAdd(&ncur[rl], 1);
            int2 v2 = make_int2(v.x & 0xFFFFF, v.y);
            if (useStg) stg[p] = v2; else ent[eb + p] = v2;
            atomicAdd(&wsum[rl], __int_as_float(v.y));
        }
    }
    __syncthreads();
    if (useStg)
        for (int i = tid; i < tot; i += 1024) ent[eb + i] = stg[i];
    if (tid < RN && n0 + tid < N) {
        rowptr[n0 + tid] = eb + nstart[tid];
        dis[n0 + tid] = rsqrtf(1.f + wsum[tid]);
    }
    if (k == 0 && tid == 0) rowptr[N] = M;
}

// ============ fallback path: global-atomic prep ============
__global__ void k_init_fb(float* deg, int* counts, int N) {
    int i = blockIdx.x * TPB + threadIdx.x;
    if (i < N) { deg[i] = 1.0f; counts[i] = 0; }
}
__global__ void k_deg_cnt_fb(const int* __restrict__ ei, const float* __restrict__ ew,
                             float* deg, int* counts, int E) {
    int e = blockIdx.x * TPB + threadIdx.x;
    if (e >= E) return;
    int r = ei[e], c = ei[E + e];
    float hw = 0.5f * ew[e];
    unsafeAtomicAdd(&deg[r], hw);
    unsafeAtomicAdd(&deg[c], hw);
    atomicAdd(&counts[r], 1);
    atomicAdd(&counts[c], 1);
}
__global__ void k_rsqrt_fb(float* degdis, int N) {
    int i = blockIdx.x * TPB + threadIdx.x;
    if (i < N) {
        float d = degdis[i];
        degdis[i] = d > 0.f ? rsqrtf(d) : 0.f;
    }
}
__global__ void k_scan_fb(const int* __restrict__ counts, int* __restrict__ rowptr,
                          int* __restrict__ cursor, int N) {
    __shared__ int partial[TPB];
    int tid = threadIdx.x;
    int chunk = (N + TPB - 1) / TPB;
    int begin = tid * chunk;
    int end = begin + chunk; if (end > N) end = N;
    int s = 0;
    for (int i = begin; i < end; ++i) s += counts[i];
    partial[tid] = s;
    __syncthreads();
    for (int off = 1; off < TPB; off <<= 1) {
        int v = partial[tid];
        int add = (tid >= off) ? partial[tid - off] : 0;
        __syncthreads();
        partial[tid] = v + add;
        __syncthreads();
    }
    int base = (tid == 0) ? 0 : partial[tid - 1];
    for (int i = begin; i < end; ++i) {
        rowptr[i] = base; cursor[i] = base;
        base += counts[i];
    }
    if (tid == TPB - 1) rowptr[N] = base;
}
__global__ void k_fill_fb(const int* __restrict__ ei, const float* __restrict__ ew,
                          int* cursor, int2* __restrict__ ent, int E) {
    int e = blockIdx.x * TPB + threadIdx.x;
    if (e >= E) return;
    int r = ei[e], c = ei[E + e];
    int hw = __float_as_int(0.5f * ew[e]);
    int p1 = atomicAdd(&cursor[r], 1);
    ent[p1] = make_int2(c, hw);
    int p2 = atomicAdd(&cursor[c], 1);
    ent[p2] = make_int2(r, hw);
}

// ---------------- standalone gemm1 / gather1 / gather2 (fallback path) ----------------
__global__ void k_gemm1(const float* __restrict__ X, const float* __restrict__ W,
                        const float* __restrict__ dis, float* __restrict__ Z, int N) {
    __shared__ float Wl[64 * 64];
    int tid = threadIdx.x;
    #pragma unroll
    for (int i = tid; i < 4096; i += TPB) Wl[i] = W[i];
    __syncthreads();
    int row = blockIdx.x * 4 + (tid >> 6);
    int f = tid & 63;
    if (row >= N) return;
    const float* xr = X + row * 64;
    float s = 0.f;
    #pragma unroll
    for (int k = 0; k < 64; ++k) s = fmaf(xr[k], Wl[k * 64 + f], s);
    Z[row * 64 + f] = dis[row] * s;
}

__global__ __launch_bounds__(TPB) void k_gather1(const float* __restrict__ Z,
    const int* __restrict__ rowptr, const long long* __restrict__ entq,
    const float* __restrict__ dis, const float* __restrict__ bias1,
    const float* __restrict__ W2, float* __restrict__ Z2, int N) {
    constexpr int UN = 16;
    __shared__ float W2l[64 * 16];
    int tid = threadIdx.x;
    #pragma unroll
    for (int i = tid; i < 1024; i += TPB) W2l[i] = W2[i];
    __syncthreads();
    int node = blockIdx.x * 4 + (tid >> 6);
    int f = tid & 63;
    if (node >= N) return;
    int sj0 = __builtin_amdgcn_readfirstlane(rowptr[node]);
    int sj1 = __builtin_amdgcn_readfirstlane(rowptr[node + 1]);
    float acc = Z[node * 64 + f];
    float dn = dis[node];
    for (int jb = sj0; jb < sj1; jb += UN) {
        long long e[UN];
        #pragma unroll
        for (int u = 0; u < UN; ++u) e[u] = entq[jb + u];
        float z[UN];
        #pragma unroll
        for (int u = 0; u < UN; ++u) {
            int nn = (jb + u < sj1) ? (int)e[u] : 0;
            z[u] = Z[nn * 64 + f];
        }
        #pragma unroll
        for (int u = 0; u < UN; ++u) {
            float ww = (jb + u < sj1) ? __int_as_float((int)(e[u] >> 32)) : 0.0f;
            acc = fmaf(ww, z[u], acc);
        }
    }
    float v = fmaf(dn, acc, bias1[f]);
    v = v > 0.f ? v : 0.f;
    int q = f >> 4, j = f & 15;
    float s = 0.f;
    #pragma unroll
    for (int i = 0; i < 16; ++i) {
        float hk = __shfl(v, 16 * q + i);
        s = fmaf(hk, W2l[(16 * q + i) * 16 + j], s);
    }
    s += __shfl_xor(s, 16);
    s += __shfl_xor(s, 32);
    if (f < 16) Z2[node * 16 + f] = dn * s;
}

__global__ __launch_bounds__(TPB) void k_gather2(const float* __restrict__ Z,
    const int* __restrict__ rowptr, const long long* __restrict__ entq,
    const float* __restrict__ dis, const float* __restrict__ bias,
    float* __restrict__ out, int N) {
    constexpr int UN = 4;
    int node = blockIdx.x * 4 + (threadIdx.x >> 6);
    int lane = threadIdx.x & 63;
    int g = lane >> 4;
    int f = lane & 15;
    if (node >= N) return;
    int sj0 = __builtin_amdgcn_readfirstlane(rowptr[node]);
    int sj1 = __builtin_amdgcn_readfirstlane(rowptr[node + 1]);
    float acc = (g == 0) ? Z[node * 16 + f] : 0.f;
    for (int jb = sj0; jb < sj1; jb += 4 * UN) {
        long long e[UN];
        #pragma unroll
        for (int u = 0; u < UN; ++u) e[u] = entq[jb + 4 * u + g];
        float z[UN], w[UN];
        #pragma unroll
        for (int u = 0; u < UN; ++u) {
            bool ok = (jb + 4 * u + g) < sj1;
            int nn = ok ? (int)e[u] : 0;
            w[u] = ok ? __int_as_float((int)(e[u] >> 32)) : 0.f;
            z[u] = Z[nn * 16 + f];
        }
        #pragma unroll
        for (int u = 0; u < UN; ++u) acc = fmaf(w[u], z[u], acc);
    }
    acc += __shfl_xor(acc, 16);
    acc += __shfl_xor(acc, 32);
    if (lane < 16) out[node * 16 + f] = fmaf(dis[node], acc, bias[f]);
}

extern "C" void kernel_launch(void* const* d_in, const int* in_sizes, int n_in,
                              void* d_out, int out_size, void* d_ws, size_t ws_size,
                              hipStream_t stream) {
    const float* x  = (const float*)d_in[0];
    const float* W1 = (const float*)d_in[1];
    const float* b1 = (const float*)d_in[2];
    const float* W2 = (const float*)d_in[3];
    const float* b2 = (const float*)d_in[4];
    const float* ew = (const float*)d_in[5];
    const int*   ei = (const int*)d_in[6];

    int N = in_sizes[0] / 64;   // 16384
    int E = in_sizes[5];        // 524288
    int M = 2 * E;

    int rsh = 0;
    while ((256 << rsh) < N) ++rsh;
    int NBe = (N + (1 << rsh) - 1) >> rsh;
    int GB  = (E + CHUNK - 1) / CHUNK;

    char* ws = (char*)d_ws;
    size_t off = 0;
    auto alloc = [&](size_t bytes) -> void* {
        void* p = ws + off;
        off += (bytes + 255) & ~(size_t)255;
        return p;
    };
    float* dis     = (float*)alloc((size_t)N * 4);
    int*   counts  = (int*)alloc((size_t)N * 4);          // fallback only
    int*   rowptr  = (int*)alloc(((size_t)N + 1) * 4);
    int*   cursor  = (int*)alloc((size_t)N * 4);          // fallback only
    int2*  ent     = (int2*)alloc(((size_t)M + 64) * 8);  // +64 pad: gather prefetch
    int*   bstartT = (int*)alloc((size_t)GB * NBe * 4);
    int*   bcntT   = (int*)alloc((size_t)GB * NBe * 4);
    int*   btot    = (int*)alloc(((size_t)NBe + 1) * 4);
    int2*  tmp     = (int2*)alloc((size_t)M * 8);         // p1 out; lower half reused as Z1
    float* Z2      = (float*)alloc((size_t)N * 16 * 4);
    (void)ws_size; (void)n_in; (void)out_size;

    float* Z1 = (float*)tmp;   // gemm1 writes only after p2 consumed tmp (grid.sync)
    float* out = (float*)d_out;

    if (N <= NMAX && GB <= GBMAX) {
        void* ka[] = {
            (void*)&x, (void*)&W1, (void*)&b1, (void*)&W2, (void*)&b2,
            (void*)&ew, (void*)&ei,
            (void*)&N, (void*)&E, (void*)&M, (void*)&rsh, (void*)&NBe, (void*)&GB,
            (void*)&dis, (void*)&rowptr, (void*)&ent,
            (void*)&bstartT, (void*)&bcntT, (void*)&btot,
            (void*)&tmp, (void*)&Z1, (void*)&Z2, (void*)&out
        };
        hipError_t rc = hipLaunchCooperativeKernel((const void*)k_mega,
                                                   dim3(MGB), dim3(1024), ka, 0, stream);
        if (rc != hipSuccess) {
            // fallback: proven 6-kernel sequence
            k_p1<<<GB, 1024, 0, stream>>>(ei, ew, E, rsh, NBe, GB, bstartT, bcntT, tmp);
            k_colsum<<<NBe, TPB, 0, stream>>>(bcntT, GB, btot);
            k_p2<<<NBe, 1024, 0, stream>>>(tmp, bstartT, bcntT, btot, GB, rsh, N, NBe, M,
                                           ent, rowptr, dis);
            k_gemm1<<<(N + 3) / 4, TPB, 0, stream>>>(x, W1, dis, Z1, N);
            k_gather1<<<(N + 3) / 4, TPB, 0, stream>>>(Z1, rowptr, (const long long*)ent,
                                                       dis, b1, W2, Z2, N);
            k_gather2<<<(N + 3) / 4, TPB, 0, stream>>>(Z2, rowptr, (const long long*)ent,
                                                       dis, b2, out, N);
        }
    } else {
        k_init_fb<<<(N + TPB - 1) / TPB, TPB, 0, stream>>>(dis, counts, N);
        k_deg_cnt_fb<<<(E + TPB - 1) / TPB, TPB, 0, stream>>>(ei, ew, dis, counts, E);
        k_rsqrt_fb<<<(N + TPB - 1) / TPB, TPB, 0, stream>>>(dis, N);
        k_scan_fb<<<1, TPB, 0, stream>>>(counts, rowptr, cursor, N);
        k_fill_fb<<<(E + TPB - 1) / TPB, TPB, 0, stream>>>(ei, ew, cursor, ent, E);
        k_gemm1<<<(N + 3) / 4, TPB, 0, stream>>>(x, W1, dis, Z1, N);
        k_gather1<<<(N + 3) / 4, TPB, 0, stream>>>(Z1, rowptr, (const long long*)ent,
                                                   dis, b1, W2, Z2, N);
        k_gather2<<<(N + 3) / 4, TPB, 0, stream>>>(Z2, rowptr, (const long long*)ent,
                                                   dis, b2, out, N);
    }
}

// Round 8
// 153.687 us; speedup vs baseline: 2.4275x; 2.4275x over previous
//
#include <hip/hip_runtime.h>

constexpr int TPB   = 256;    // generic block
constexpr int NMAX  = 16384;  // fast-path cap (node ids fit 20 bits, rloc 6 bits)
constexpr int CHUNK = 2048;   // edges per k_p1 block
constexpr int GBMAX = 1024;   // fast-path cap on p1 grid
constexpr int STGN  = 12288;  // k_p2 LDS staging entries (96 KB; bucket mean 8192, sigma~90)
constexpr int RCAP  = 12;     // register-held entries/thread in k_p2 (covers segment len <= 48)

// edge_index delivered as int32 [2][E] (validated R3 counters + R6 pass).

// ============ fast path: two-level bucket CSR build, coalesced writes ============
// bucket = node >> rsh (RN = 1<<rsh <= 64 nodes/bucket, NBe = ceil(N/RN) <= 256)
// Tables stored TRANSPOSED [k*GB + b] so column ops are contiguous.

// ---- p1: partition edge-endpoint entries into per-(block,bucket) runs in tmp.
//      btot[k] accumulated here via global atomics (colsum kernel eliminated;
//      btot pre-zeroed by a 1KB hipMemsetAsync). ----
__global__ __launch_bounds__(1024) void k_p1(const int* __restrict__ ei,
    const float* __restrict__ ew, int E, int rsh, int NBe, int GB,
    int* __restrict__ bstartT, int* __restrict__ bcntT, int* __restrict__ btot,
    int2* __restrict__ tmp) {
    __shared__ int cnt[256];
    __shared__ int curs[256];
    __shared__ int sc[256];
    __shared__ int2 stg[2 * CHUNK];   // 32 KB
    int tid = threadIdx.x;
    int b = blockIdx.x;
    int e0 = b * CHUNK;
    int e1 = min(E, e0 + CHUNK);
    if (tid < NBe) cnt[tid] = 0;
    __syncthreads();
    int ea = e0 + tid, ebg = e0 + 1024 + tid;
    int r0 = 0, c0 = 0, r1 = 0, c1 = 0, w0 = 0, w1 = 0;
    bool va = ea < e1, vb = ebg < e1;
    if (va) { r0 = ei[ea];  c0 = ei[E + ea];  w0 = __float_as_int(0.5f * ew[ea]); }
    if (vb) { r1 = ei[ebg]; c1 = ei[E + ebg]; w1 = __float_as_int(0.5f * ew[ebg]); }
    if (va) { atomicAdd(&cnt[r0 >> rsh], 1); atomicAdd(&cnt[c0 >> rsh], 1); }
    if (vb) { atomicAdd(&cnt[r1 >> rsh], 1); atomicAdd(&cnt[c1 >> rsh], 1); }
    __syncthreads();
    int myc = (tid < NBe) ? cnt[tid] : 0;
    if (tid < NBe) sc[tid] = myc;
    __syncthreads();
    for (int off = 1; off < NBe; off <<= 1) {
        int v = 0;
        if (tid < NBe && tid >= off) v = sc[tid - off];
        __syncthreads();
        if (tid < NBe) sc[tid] += v;
        __syncthreads();
    }
    if (tid < NBe) {
        int excl = sc[tid] - myc;
        curs[tid] = excl;
        bstartT[tid * GB + b] = 2 * e0 + excl;   // transposed
        bcntT[tid * GB + b] = myc;
        if (myc) atomicAdd(&btot[tid], myc);     // colsum fused (device-scope atomic)
    }
    __syncthreads();
    int mask = (1 << rsh) - 1;
    if (va) {
        int p = atomicAdd(&curs[r0 >> rsh], 1);
        stg[p] = make_int2(((r0 & mask) << 20) | c0, w0);
        p = atomicAdd(&curs[c0 >> rsh], 1);
        stg[p] = make_int2(((c0 & mask) << 20) | r0, w0);
    }
    if (vb) {
        int p = atomicAdd(&curs[r1 >> rsh], 1);
        stg[p] = make_int2(((r1 & mask) << 20) | c1, w1);
        p = atomicAdd(&curs[c1 >> rsh], 1);
        stg[p] = make_int2(((c1 & mask) << 20) | r1, w1);
    }
    __syncthreads();
    int tot = 2 * (e1 - e0);
    for (int i = tid; i < tot; i += 1024) tmp[2 * e0 + i] = stg[i];  // coalesced burst
}

// ---- p2: per-bucket local sort. SINGLE tmp read (register prefetch), LDS-staged
//      coalesced ent writes; cheap btot scan for eb/tot. ----
__global__ __launch_bounds__(1024) void k_p2(const int2* __restrict__ tmp,
    const int* __restrict__ bstartT, const int* __restrict__ bcntT,
    const int* __restrict__ btot, int GB, int rsh, int N, int NBe, int M,
    int2* __restrict__ ent, int* __restrict__ rowptr, float* __restrict__ dis) {
    __shared__ int sco[256];
    __shared__ int ncnt[64];
    __shared__ int nstart[64];
    __shared__ int ncur[64];
    __shared__ float wsum[64];
    __shared__ int2 stg[STGN];        // 96 KB staging for this bucket's CSR slice
    int k = blockIdx.x;
    int tid = threadIdx.x;
    int RN = 1 << rsh;
    int n0 = k << rsh;
    const int base = k * GB;

    // issue my segment-slice loads EARLY — latency hides under the btot scan barriers
    int grp = tid >> 2, sub = tid & 3;   // 4 threads per source-block segment
    int s0 = 0, l0 = 0;
    if (grp < GB) { s0 = bstartT[base + grp]; l0 = bcntT[base + grp]; }
    int2 r[RCAP];
    #pragma unroll
    for (int u = 0; u < RCAP; ++u) {
        int idx = sub + 4 * u;
        if (idx < l0) r[u] = tmp[s0 + idx];
    }

    // fused: exclusive scan of btot -> eb (1 KB, each block does it locally)
    int bt = (tid < NBe) ? btot[tid] : 0;
    if (tid < 256) sco[tid] = bt;
    if (tid < RN) { ncnt[tid] = 0; wsum[tid] = 0.f; }
    __syncthreads();
    for (int off = 1; off < 256; off <<= 1) {
        int v = 0;
        if (tid < 256 && tid >= off) v = sco[tid - off];
        __syncthreads();
        if (tid < 256) sco[tid] += v;
        __syncthreads();
    }
    int eb = sco[k] - btot[k];
    int tot = btot[k];
    bool useStg = (tot <= STGN);

    // ---- Phase A: node-local histogram from registers (tails read tmp direct) ----
    #pragma unroll
    for (int u = 0; u < RCAP; ++u)
        if (sub + 4 * u < l0) atomicAdd(&ncnt[r[u].x >> 20], 1);
    for (int idx = sub + 4 * RCAP; idx < l0; idx += 4)            // rare overflow tail
        atomicAdd(&ncnt[tmp[s0 + idx].x >> 20], 1);
    for (int b = grp + 256; b < GB; b += 256) {                   // generic GB > 256
        int s = bstartT[base + b], l = bcntT[base + b];
        for (int idx = sub; idx < l; idx += 4)
            atomicAdd(&ncnt[tmp[s + idx].x >> 20], 1);
    }
    __syncthreads();

    // ---- exclusive scan of ncnt over RN (<= 64) ----
    int myc = (tid < RN) ? ncnt[tid] : 0;
    if (tid < RN) nstart[tid] = myc;
    __syncthreads();
    for (int off = 1; off < RN; off <<= 1) {
        int v = 0;
        if (tid < RN && tid >= off) v = nstart[tid - off];
        __syncthreads();
        if (tid < RN) nstart[tid] += v;
        __syncthreads();
    }
    if (tid < RN) { nstart[tid] -= myc; ncur[tid] = nstart[tid]; }
    __syncthreads();

    // ---- Phase B: scatter from registers (LDS staging when it fits) + weight sums ----
    #pragma unroll
    for (int u = 0; u < RCAP; ++u)
        if (sub + 4 * u < l0) {
            int rl = r[u].x >> 20;
            int p = atomicAdd(&ncur[rl], 1);
            int2 v2 = make_int2(r[u].x & 0xFFFFF, r[u].y);
            if (useStg) stg[p] = v2; else ent[eb + p] = v2;
            atomicAdd(&wsum[rl], __int_as_float(r[u].y));
        }
    for (int idx = sub + 4 * RCAP; idx < l0; idx += 4) {          // rare overflow tail
        int2 v = tmp[s0 + idx];
        int rl = v.x >> 20;
        int p = atomicAdd(&ncur[rl], 1);
        int2 v2 = make_int2(v.x & 0xFFFFF, v.y);
        if (useStg) stg[p] = v2; else ent[eb + p] = v2;
        atomicAdd(&wsum[rl], __int_as_float(v.y));
    }
    for (int b = grp + 256; b < GB; b += 256) {                   // generic GB > 256
        int s = bstartT[base + b], l = bcntT[base + b];
        for (int idx = sub; idx < l; idx += 4) {
            int2 v = tmp[s + idx];
            int rl = v.x >> 20;
            int p = atomicAdd(&ncur[rl], 1);
            int2 v2 = make_int2(v.x & 0xFFFFF, v.y);
            if (useStg) stg[p] = v2; else ent[eb + p] = v2;
            atomicAdd(&wsum[rl], __int_as_float(v.y));
        }
    }
    __syncthreads();
    if (useStg)
        for (int i = tid; i < tot; i += 1024) ent[eb + i] = stg[i];  // coalesced burst
    if (tid < RN && n0 + tid < N) {
        rowptr[n0 + tid] = eb + nstart[tid];
        dis[n0 + tid] = rsqrtf(1.f + wsum[tid]);
    }
    if (k == 0 && tid == 0) rowptr[N] = M;
}

// ============ fallback path: global-atomic prep ============
__global__ void k_init_fb(float* deg, int* counts, int N) {
    int i = blockIdx.x * TPB + threadIdx.x;
    if (i < N) { deg[i] = 1.0f; counts[i] = 0; }
}
__global__ void k_deg_cnt_fb(const int* __restrict__ ei, const float* __restrict__ ew,
                             float* deg, int* counts, int E) {
    int e = blockIdx.x * TPB + threadIdx.x;
    if (e >= E) return;
    int r = ei[e], c = ei[E + e];
    float hw = 0.5f * ew[e];
    unsafeAtomicAdd(&deg[r], hw);
    unsafeAtomicAdd(&deg[c], hw);
    atomicAdd(&counts[r], 1);
    atomicAdd(&counts[c], 1);
}
__global__ void k_rsqrt_fb(float* degdis, int N) {
    int i = blockIdx.x * TPB + threadIdx.x;
    if (i < N) {
        float d = degdis[i];
        degdis[i] = d > 0.f ? rsqrtf(d) : 0.f;
    }
}
__global__ void k_scan_fb(const int* __restrict__ counts, int* __restrict__ rowptr,
                          int* __restrict__ cursor, int N) {
    __shared__ int partial[TPB];
    int tid = threadIdx.x;
    int chunk = (N + TPB - 1) / TPB;
    int begin = tid * chunk;
    int end = begin + chunk; if (end > N) end = N;
    int s = 0;
    for (int i = begin; i < end; ++i) s += counts[i];
    partial[tid] = s;
    __syncthreads();
    for (int off = 1; off < TPB; off <<= 1) {
        int v = partial[tid];
        int add = (tid >= off) ? partial[tid - off] : 0;
        __syncthreads();
        partial[tid] = v + add;
        __syncthreads();
    }
    int base = (tid == 0) ? 0 : partial[tid - 1];
    for (int i = begin; i < end; ++i) {
        rowptr[i] = base; cursor[i] = base;
        base += counts[i];
    }
    if (tid == TPB - 1) rowptr[N] = base;
}
__global__ void k_fill_fb(const int* __restrict__ ei, const float* __restrict__ ew,
                          int* cursor, int2* __restrict__ ent, int E) {
    int e = blockIdx.x * TPB + threadIdx.x;
    if (e >= E) return;
    int r = ei[e], c = ei[E + e];
    int hw = __float_as_int(0.5f * ew[e]);
    int p1 = atomicAdd(&cursor[r], 1);
    ent[p1] = make_int2(c, hw);
    int p2 = atomicAdd(&cursor[c], 1);
    ent[p2] = make_int2(r, hw);
}

// ---------------- Z1[N,64] = dis .* (X[N,64] @ W1[64,64]) ----------------
__global__ void k_gemm1(const float* __restrict__ X, const float* __restrict__ W,
                        const float* __restrict__ dis, float* __restrict__ Z, int N) {
    __shared__ float Wl[64 * 64];
    int tid = threadIdx.x;
    #pragma unroll
    for (int i = tid; i < 4096; i += TPB) Wl[i] = W[i];
    __syncthreads();
    int row = blockIdx.x * 4 + (tid >> 6);
    int f = tid & 63;
    if (row >= N) return;
    const float* xr = X + row * 64;
    float s = 0.f;
    #pragma unroll
    for (int k = 0; k < 64; ++k) s = fmaf(xr[k], Wl[k * 64 + f], s);
    Z[row * 64 + f] = dis[row] * s;
}

// ---- layer-1 gather FUSED with gemm2, wave-private epilogue.
//      SCALAR entry path: one wave per node -> ent indices are wave-uniform ->
//      s_load the (neighbor,weight) stream into SGPRs (no ds_bpermute, no vector
//      address math; Z-row loads use SGPR base + lane offset). Tail masked by
//      scalar cselect (w=0, n=0); ent's +64 pad makes unguarded s_loads safe. ----
__global__ __launch_bounds__(TPB) void k_gather1(const float* __restrict__ Z,
    const int* __restrict__ rowptr, const long long* __restrict__ entq,
    const float* __restrict__ dis, const float* __restrict__ bias1,
    const float* __restrict__ W2, float* __restrict__ Z2, int N) {
    constexpr int UN = 16;
    __shared__ float W2l[64 * 16];    // 4 KB
    int tid = threadIdx.x;
    #pragma unroll
    for (int i = tid; i < 1024; i += TPB) W2l[i] = W2[i];
    __syncthreads();                  // ONCE, before the divergent gather — no wave coupling
    int node = blockIdx.x * 4 + (tid >> 6);   // one wave per node
    int f = tid & 63;
    if (node >= N) return;
    // wave-uniform row bounds -> scalar registers
    int sj0 = __builtin_amdgcn_readfirstlane(rowptr[node]);
    int sj1 = __builtin_amdgcn_readfirstlane(rowptr[node + 1]);
    float acc = Z[node * 64 + f];
    float dn = dis[node];
    for (int jb = sj0; jb < sj1; jb += UN) {
        long long e[UN];
        #pragma unroll
        for (int u = 0; u < UN; ++u) e[u] = entq[jb + u];   // uniform -> s_load (pad-safe)
        float z[UN];
        #pragma unroll
        for (int u = 0; u < UN; ++u) {
            int nn = (jb + u < sj1) ? (int)e[u] : 0;        // scalar cselect
            z[u] = Z[nn * 64 + f];                          // saddr-form coalesced 256B
        }
        #pragma unroll
        for (int u = 0; u < UN; ++u) {
            float ww = (jb + u < sj1) ? __int_as_float((int)(e[u] >> 32)) : 0.0f;
            acc = fmaf(ww, z[u], acc);                      // SGPR weight operand
        }
    }
    float v = fmaf(dn, acc, bias1[f]);
    v = v > 0.f ? v : 0.f;            // H[node][f] lives in this lane
    // wave-private epilogue: Z2[node, j] = dn * sum_k H[k] * W2[k][j]
    // lane f covers output j = f&15 over k-quarter q = f>>4, then xor-reduce quarters.
    int q = f >> 4, j = f & 15;
    float s = 0.f;
    #pragma unroll
    for (int i = 0; i < 16; ++i) {
        float hk = __shfl(v, 16 * q + i);
        s = fmaf(hk, W2l[(16 * q + i) * 16 + j], s);
    }
    s += __shfl_xor(s, 16);
    s += __shfl_xor(s, 32);
    if (f < 16) Z2[node * 16 + f] = dn * s;
}

// ---- layer-2 gather: scalar lanes (16/node), pipelined tiles, 16-deep batches ----
template <int D, bool RELU>
__global__ void k_gather(const float* __restrict__ Z, const int* __restrict__ rowptr,
                         const long long* __restrict__ entq, const float* __restrict__ dis,
                         const float* __restrict__ bias, float* __restrict__ out, int N) {
    constexpr int NPB = TPB / D;
    constexpr int UN = 16;                      // outstanding neighbor rows per batch
    int node = blockIdx.x * NPB + threadIdx.x / D;
    int f = threadIdx.x % D;
    int lane = threadIdx.x & 63;
    int base = lane & ~(D - 1);
    if (node >= N) return;
    int j0 = rowptr[node], j1 = rowptr[node + 1];
    float acc = Z[node * D + f];
    long long cur = 0;
    if (j0 < j1) cur = __builtin_nontemporal_load(entq + j0 + f);  // ent padded by 64
    for (int jb = j0; jb < j1; jb += D) {
        long long nxt = cur;
        if (jb + D < j1) nxt = __builtin_nontemporal_load(entq + jb + D + f);
        int ex = (int)cur;
        float ey = __int_as_float((int)(cur >> 32));
        int cnt = j1 - jb; if (cnt > D) cnt = D;
        int k = 0;
        for (; k + UN <= cnt; k += UN) {
            int n[UN]; float w[UN], z[UN];
            #pragma unroll
            for (int u = 0; u < UN; ++u) {
                n[u] = __shfl(ex, base + k + u);
                w[u] = __shfl(ey, base + k + u);
            }
            #pragma unroll
            for (int u = 0; u < UN; ++u) z[u] = Z[n[u] * D + f];  // 16 rows in flight
            #pragma unroll
            for (int u = 0; u < UN; ++u) acc = fmaf(w[u], z[u], acc);
        }
        for (; k < cnt; ++k) {
            int n0 = __shfl(ex, base + k);
            float w0 = __shfl(ey, base + k);
            acc = fmaf(w0, Z[n0 * D + f], acc);
        }
        cur = nxt;
    }
    float v = fmaf(dis[node], acc, bias[f]);
    if (RELU) v = v > 0.f ? v : 0.f;
    out[node * D + f] = v;
}

extern "C" void kernel_launch(void* const* d_in, const int* in_sizes, int n_in,
                              void* d_out, int out_size, void* d_ws, size_t ws_size,
                              hipStream_t stream) {
    const float* x  = (const float*)d_in[0];
    const float* W1 = (const float*)d_in[1];
    const float* b1 = (const float*)d_in[2];
    const float* W2 = (const float*)d_in[3];
    const float* b2 = (const float*)d_in[4];
    const float* ew = (const float*)d_in[5];
    const int*   ei = (const int*)d_in[6];   // int32 layout (validated)

    const int N = in_sizes[0] / 64;   // 16384
    const int E = in_sizes[5];        // 524288
    const int M = 2 * E;              // CSR entries

    // bucket geometry: RN = pow2 <= 64, NBe = ceil(N/RN) <= 256
    int rsh = 0;
    while ((256 << rsh) < N) ++rsh;
    const int NBe = (N + (1 << rsh) - 1) >> rsh;
    const int GB  = (E + CHUNK - 1) / CHUNK;

    char* ws = (char*)d_ws;
    size_t off = 0;
    auto alloc = [&](size_t bytes) -> void* {
        void* p = ws + off;
        off += (bytes + 255) & ~(size_t)255;
        return p;
    };
    float* dis     = (float*)alloc((size_t)N * 4);
    int*   counts  = (int*)alloc((size_t)N * 4);          // fallback only
    int*   rowptr  = (int*)alloc(((size_t)N + 1) * 4);
    int*   cursor  = (int*)alloc((size_t)N * 4);          // fallback only
    int2*  ent     = (int2*)alloc(((size_t)M + 64) * 8);  // +64 pad: gather tile prefetch
    int*   bstartT = (int*)alloc((size_t)GB * NBe * 4);   // [k*GB + b]
    int*   bcntT   = (int*)alloc((size_t)GB * NBe * 4);   // [k*GB + b]
    int*   btot    = (int*)alloc(((size_t)NBe + 1) * 4);
    int2*  tmp     = (int2*)alloc((size_t)M * 8);         // p1 output; lower half re-used as Z1
    float* Z2      = (float*)alloc((size_t)N * 16 * 4);
    (void)ws_size; (void)n_in; (void)out_size;

    // Z1 aliases tmp's lower 4 MB: k_gemm1 writes it only AFTER k_p2 consumed tmp.
    float* Z1 = (float*)tmp;

    float* out = (float*)d_out;

    if (N <= NMAX && GB <= GBMAX) {
        hipMemsetAsync(btot, 0, ((size_t)NBe + 1) * 4, stream);   // p1 accumulates into it
        k_p1<<<GB, 1024, 0, stream>>>(ei, ew, E, rsh, NBe, GB, bstartT, bcntT, btot, tmp);
        k_p2<<<NBe, 1024, 0, stream>>>(tmp, bstartT, bcntT, btot, GB, rsh, N, NBe, M,
                                       ent, rowptr, dis);
    } else {
        k_init_fb<<<(N + TPB - 1) / TPB, TPB, 0, stream>>>(dis, counts, N);
        k_deg_cnt_fb<<<(E + TPB - 1) / TPB, TPB, 0, stream>>>(ei, ew, dis, counts, E);
        k_rsqrt_fb<<<(N + TPB - 1) / TPB, TPB, 0, stream>>>(dis, N);
        k_scan_fb<<<1, TPB, 0, stream>>>(counts, rowptr, cursor, N);
        k_fill_fb<<<(E + TPB - 1) / TPB, TPB, 0, stream>>>(ei, ew, cursor, ent, E);
    }

    // layer 1: gemm1 -> fused gather+gemm2 (H never leaves the CU)
    k_gemm1<<<(N + 3) / 4, TPB, 0, stream>>>(x, W1, dis, Z1, N);
    k_gather1<<<(N + 3) / 4, TPB, 0, stream>>>(Z1, rowptr, (const long long*)ent,
                                               dis, b1, W2, Z2, N);
    // layer 2
    k_gather<16, false><<<(N + 15) / 16, TPB, 0, stream>>>(Z2, rowptr, (const long long*)ent,
                                                           dis, b2, out, N);
}

// Round 9
// 147.436 us; speedup vs baseline: 2.5304x; 1.0424x over previous
//
#include <hip/hip_runtime.h>

constexpr int TPB   = 256;    // generic block
constexpr int NMAX  = 16384;  // fast-path cap (node ids fit 20 bits, rloc 6 bits)
constexpr int CHUNK = 2048;   // edges per k_p1 block
constexpr int GBMAX = 1024;   // fast-path cap on p1 grid
constexpr int STGN  = 12288;  // k_p2 LDS staging entries (96 KB; bucket mean 8192, sigma~90)
constexpr int RCAP  = 12;     // register-held entries/thread in k_p2 (covers segment len <= 48)

// edge_index delivered as int32 [2][E] (validated R3 counters + R6 pass).

// ============ fast path: two-level bucket CSR build, coalesced writes ============
// bucket = node >> rsh (RN = 1<<rsh <= 64 nodes/bucket, NBe = ceil(N/RN) <= 256)
// Tables stored TRANSPOSED [k*GB + b] so column ops are contiguous.

// ---- p1: partition edge-endpoint entries into per-(block,bucket) runs in tmp ----
__global__ __launch_bounds__(1024) void k_p1(const int* __restrict__ ei,
    const float* __restrict__ ew, int E, int rsh, int NBe, int GB,
    int* __restrict__ bstartT, int* __restrict__ bcntT, int2* __restrict__ tmp) {
    __shared__ int cnt[256];
    __shared__ int curs[256];
    __shared__ int sc[256];
    __shared__ int2 stg[2 * CHUNK];   // 32 KB
    int tid = threadIdx.x;
    int b = blockIdx.x;
    int e0 = b * CHUNK;
    int e1 = min(E, e0 + CHUNK);
    if (tid < NBe) cnt[tid] = 0;
    __syncthreads();
    int ea = e0 + tid, ebg = e0 + 1024 + tid;
    int r0 = 0, c0 = 0, r1 = 0, c1 = 0, w0 = 0, w1 = 0;
    bool va = ea < e1, vb = ebg < e1;
    if (va) { r0 = ei[ea];  c0 = ei[E + ea];  w0 = __float_as_int(0.5f * ew[ea]); }
    if (vb) { r1 = ei[ebg]; c1 = ei[E + ebg]; w1 = __float_as_int(0.5f * ew[ebg]); }
    if (va) { atomicAdd(&cnt[r0 >> rsh], 1); atomicAdd(&cnt[c0 >> rsh], 1); }
    if (vb) { atomicAdd(&cnt[r1 >> rsh], 1); atomicAdd(&cnt[c1 >> rsh], 1); }
    __syncthreads();
    int myc = (tid < NBe) ? cnt[tid] : 0;
    if (tid < NBe) sc[tid] = myc;
    __syncthreads();
    for (int off = 1; off < NBe; off <<= 1) {
        int v = 0;
        if (tid < NBe && tid >= off) v = sc[tid - off];
        __syncthreads();
        if (tid < NBe) sc[tid] += v;
        __syncthreads();
    }
    if (tid < NBe) {
        int excl = sc[tid] - myc;
        curs[tid] = excl;
        bstartT[tid * GB + b] = 2 * e0 + excl;   // transposed
        bcntT[tid * GB + b] = myc;
    }
    __syncthreads();
    int mask = (1 << rsh) - 1;
    if (va) {
        int p = atomicAdd(&curs[r0 >> rsh], 1);
        stg[p] = make_int2(((r0 & mask) << 20) | c0, w0);
        p = atomicAdd(&curs[c0 >> rsh], 1);
        stg[p] = make_int2(((c0 & mask) << 20) | r0, w0);
    }
    if (vb) {
        int p = atomicAdd(&curs[r1 >> rsh], 1);
        stg[p] = make_int2(((r1 & mask) << 20) | c1, w1);
        p = atomicAdd(&curs[c1 >> rsh], 1);
        stg[p] = make_int2(((c1 & mask) << 20) | r1, w1);
    }
    __syncthreads();
    int tot = 2 * (e1 - e0);
    for (int i = tid; i < tot; i += 1024) tmp[2 * e0 + i] = stg[i];  // coalesced burst
}

// ---- colsum: one block per bucket, contiguous coalesced row sum -> btot[k] ----
__global__ void k_colsum(const int* __restrict__ bcntT, int GB,
                         int* __restrict__ btot) {
    __shared__ int red[TPB / 64];
    int k = blockIdx.x;
    int s = 0;
    for (int b = threadIdx.x; b < GB; b += TPB) s += bcntT[k * GB + b];
    #pragma unroll
    for (int off = 32; off; off >>= 1) s += __shfl_down(s, off, 64);
    int wv = threadIdx.x >> 6;
    if ((threadIdx.x & 63) == 0) red[wv] = s;
    __syncthreads();
    if (threadIdx.x == 0) {
        int t = 0;
        for (int w = 0; w < TPB / 64; ++w) t += red[w];
        btot[k] = t;
    }
}

// ---- p2: per-bucket local sort. SINGLE tmp read (register prefetch), LDS-staged
//      coalesced ent writes; cheap btot scan for eb/tot (colsum kept). ----
__global__ __launch_bounds__(1024) void k_p2(const int2* __restrict__ tmp,
    const int* __restrict__ bstartT, const int* __restrict__ bcntT,
    const int* __restrict__ btot, int GB, int rsh, int N, int NBe, int M,
    int2* __restrict__ ent, int* __restrict__ rowptr, float* __restrict__ dis) {
    __shared__ int sco[256];
    __shared__ int ncnt[64];
    __shared__ int nstart[64];
    __shared__ int ncur[64];
    __shared__ float wsum[64];
    __shared__ int2 stg[STGN];        // 96 KB staging for this bucket's CSR slice
    int k = blockIdx.x;
    int tid = threadIdx.x;
    int RN = 1 << rsh;
    int n0 = k << rsh;
    const int base = k * GB;

    // issue my segment-slice loads EARLY — latency hides under the btot scan barriers
    int grp = tid >> 2, sub = tid & 3;   // 4 threads per source-block segment
    int s0 = 0, l0 = 0;
    if (grp < GB) { s0 = bstartT[base + grp]; l0 = bcntT[base + grp]; }
    int2 r[RCAP];
    #pragma unroll
    for (int u = 0; u < RCAP; ++u) {
        int idx = sub + 4 * u;
        if (idx < l0) r[u] = tmp[s0 + idx];
    }

    // fused: exclusive scan of btot -> eb (1 KB, each block does it locally)
    int bt = (tid < NBe) ? btot[tid] : 0;
    if (tid < 256) sco[tid] = bt;
    if (tid < RN) { ncnt[tid] = 0; wsum[tid] = 0.f; }
    __syncthreads();
    for (int off = 1; off < 256; off <<= 1) {
        int v = 0;
        if (tid < 256 && tid >= off) v = sco[tid - off];
        __syncthreads();
        if (tid < 256) sco[tid] += v;
        __syncthreads();
    }
    int eb = sco[k] - btot[k];
    int tot = btot[k];
    bool useStg = (tot <= STGN);

    // ---- Phase A: node-local histogram from registers (tails read tmp direct) ----
    #pragma unroll
    for (int u = 0; u < RCAP; ++u)
        if (sub + 4 * u < l0) atomicAdd(&ncnt[r[u].x >> 20], 1);
    for (int idx = sub + 4 * RCAP; idx < l0; idx += 4)            // rare overflow tail
        atomicAdd(&ncnt[tmp[s0 + idx].x >> 20], 1);
    for (int b = grp + 256; b < GB; b += 256) {                   // generic GB > 256
        int s = bstartT[base + b], l = bcntT[base + b];
        for (int idx = sub; idx < l; idx += 4)
            atomicAdd(&ncnt[tmp[s + idx].x >> 20], 1);
    }
    __syncthreads();

    // ---- exclusive scan of ncnt over RN (<= 64) ----
    int myc = (tid < RN) ? ncnt[tid] : 0;
    if (tid < RN) nstart[tid] = myc;
    __syncthreads();
    for (int off = 1; off < RN; off <<= 1) {
        int v = 0;
        if (tid < RN && tid >= off) v = nstart[tid - off];
        __syncthreads();
        if (tid < RN) nstart[tid] += v;
        __syncthreads();
    }
    if (tid < RN) { nstart[tid] -= myc; ncur[tid] = nstart[tid]; }
    __syncthreads();

    // ---- Phase B: scatter from registers (LDS staging when it fits) + weight sums ----
    #pragma unroll
    for (int u = 0; u < RCAP; ++u)
        if (sub + 4 * u < l0) {
            int rl = r[u].x >> 20;
            int p = atomicAdd(&ncur[rl], 1);
            int2 v2 = make_int2(r[u].x & 0xFFFFF, r[u].y);
            if (useStg) stg[p] = v2; else ent[eb + p] = v2;
            atomicAdd(&wsum[rl], __int_as_float(r[u].y));
        }
    for (int idx = sub + 4 * RCAP; idx < l0; idx += 4) {          // rare overflow tail
        int2 v = tmp[s0 + idx];
        int rl = v.x >> 20;
        int p = atomicAdd(&ncur[rl], 1);
        int2 v2 = make_int2(v.x & 0xFFFFF, v.y);
        if (useStg) stg[p] = v2; else ent[eb + p] = v2;
        atomicAdd(&wsum[rl], __int_as_float(v.y));
    }
    for (int b = grp + 256; b < GB; b += 256) {                   // generic GB > 256
        int s = bstartT[base + b], l = bcntT[base + b];
        for (int idx = sub; idx < l; idx += 4) {
            int2 v = tmp[s + idx];
            int rl = v.x >> 20;
            int p = atomicAdd(&ncur[rl], 1);
            int2 v2 = make_int2(v.x & 0xFFFFF, v.y);
            if (useStg) stg[p] = v2; else ent[eb + p] = v2;
            atomicAdd(&wsum[rl], __int_as_float(v.y));
        }
    }
    __syncthreads();
    if (useStg)
        for (int i = tid; i < tot; i += 1024) ent[eb + i] = stg[i];  // coalesced burst
    if (tid < RN && n0 + tid < N) {
        rowptr[n0 + tid] = eb + nstart[tid];
        dis[n0 + tid] = rsqrtf(1.f + wsum[tid]);
    }
    if (k == 0 && tid == 0) rowptr[N] = M;
}

// ============ fallback path: global-atomic prep ============
__global__ void k_init_fb(float* deg, int* counts, int N) {
    int i = blockIdx.x * TPB + threadIdx.x;
    if (i < N) { deg[i] = 1.0f; counts[i] = 0; }
}
__global__ void k_deg_cnt_fb(const int* __restrict__ ei, const float* __restrict__ ew,
                             float* deg, int* counts, int E) {
    int e = blockIdx.x * TPB + threadIdx.x;
    if (e >= E) return;
    int r = ei[e], c = ei[E + e];
    float hw = 0.5f * ew[e];
    unsafeAtomicAdd(&deg[r], hw);
    unsafeAtomicAdd(&deg[c], hw);
    atomicAdd(&counts[r], 1);
    atomicAdd(&counts[c], 1);
}
__global__ void k_rsqrt_fb(float* degdis, int N) {
    int i = blockIdx.x * TPB + threadIdx.x;
    if (i < N) {
        float d = degdis[i];
        degdis[i] = d > 0.f ? rsqrtf(d) : 0.f;
    }
}
__global__ void k_scan_fb(const int* __restrict__ counts, int* __restrict__ rowptr,
                          int* __restrict__ cursor, int N) {
    __shared__ int partial[TPB];
    int tid = threadIdx.x;
    int chunk = (N + TPB - 1) / TPB;
    int begin = tid * chunk;
    int end = begin + chunk; if (end > N) end = N;
    int s = 0;
    for (int i = begin; i < end; ++i) s += counts[i];
    partial[tid] = s;
    __syncthreads();
    for (int off = 1; off < TPB; off <<= 1) {
        int v = partial[tid];
        int add = (tid >= off) ? partial[tid - off] : 0;
        __syncthreads();
        partial[tid] = v + add;
        __syncthreads();
    }
    int base = (tid == 0) ? 0 : partial[tid - 1];
    for (int i = begin; i < end; ++i) {
        rowptr[i] = base; cursor[i] = base;
        base += counts[i];
    }
    if (tid == TPB - 1) rowptr[N] = base;
}
__global__ void k_fill_fb(const int* __restrict__ ei, const float* __restrict__ ew,
                          int* cursor, int2* __restrict__ ent, int E) {
    int e = blockIdx.x * TPB + threadIdx.x;
    if (e >= E) return;
    int r = ei[e], c = ei[E + e];
    int hw = __float_as_int(0.5f * ew[e]);
    int p1 = atomicAdd(&cursor[r], 1);
    ent[p1] = make_int2(c, hw);
    int p2 = atomicAdd(&cursor[c], 1);
    ent[p2] = make_int2(r, hw);
}

// ---------------- Z1[N,64] = dis .* (X[N,64] @ W1[64,64]) ----------------
__global__ void k_gemm1(const float* __restrict__ X, const float* __restrict__ W,
                        const float* __restrict__ dis, float* __restrict__ Z, int N) {
    __shared__ float Wl[64 * 64];
    int tid = threadIdx.x;
    #pragma unroll
    for (int i = tid; i < 4096; i += TPB) Wl[i] = W[i];
    __syncthreads();
    int row = blockIdx.x * 4 + (tid >> 6);
    int f = tid & 63;
    if (row >= N) return;
    const float* xr = X + row * 64;
    float s = 0.f;
    #pragma unroll
    for (int k = 0; k < 64; ++k) s = fmaf(xr[k], Wl[k * 64 + f], s);
    Z[row * 64 + f] = dis[row] * s;
}

// ---- layer-1 gather FUSED with gemm2, wave-private epilogue.
//      SCALAR entry path: one wave per node -> ent indices are wave-uniform ->
//      s_load the (neighbor,weight) stream into SGPRs (no ds_bpermute, no vector
//      address math; Z-row loads use SGPR base + lane offset). Tail masked by
//      scalar cselect (w=0, n=0); ent's +64 pad makes unguarded s_loads safe. ----
__global__ __launch_bounds__(TPB) void k_gather1(const float* __restrict__ Z,
    const int* __restrict__ rowptr, const long long* __restrict__ entq,
    const float* __restrict__ dis, const float* __restrict__ bias1,
    const float* __restrict__ W2, float* __restrict__ Z2, int N) {
    constexpr int UN = 16;
    __shared__ float W2l[64 * 16];    // 4 KB
    int tid = threadIdx.x;
    #pragma unroll
    for (int i = tid; i < 1024; i += TPB) W2l[i] = W2[i];
    __syncthreads();                  // ONCE, before the divergent gather — no wave coupling
    int node = blockIdx.x * 4 + (tid >> 6);   // one wave per node
    int f = tid & 63;
    if (node >= N) return;
    // wave-uniform row bounds -> scalar registers
    int sj0 = __builtin_amdgcn_readfirstlane(rowptr[node]);
    int sj1 = __builtin_amdgcn_readfirstlane(rowptr[node + 1]);
    float acc = Z[node * 64 + f];
    float dn = dis[node];
    for (int jb = sj0; jb < sj1; jb += UN) {
        long long e[UN];
        #pragma unroll
        for (int u = 0; u < UN; ++u) e[u] = entq[jb + u];   // uniform -> s_load (pad-safe)
        float z[UN];
        #pragma unroll
        for (int u = 0; u < UN; ++u) {
            int nn = (jb + u < sj1) ? (int)e[u] : 0;        // scalar cselect
            z[u] = Z[nn * 64 + f];                          // saddr-form coalesced 256B
        }
        #pragma unroll
        for (int u = 0; u < UN; ++u) {
            float ww = (jb + u < sj1) ? __int_as_float((int)(e[u] >> 32)) : 0.0f;
            acc = fmaf(ww, z[u], acc);                      // SGPR weight operand
        }
    }
    float v = fmaf(dn, acc, bias1[f]);
    v = v > 0.f ? v : 0.f;            // H[node][f] lives in this lane
    // wave-private epilogue: Z2[node, j] = dn * sum_k H[k] * W2[k][j]
    // lane f covers output j = f&15 over k-quarter q = f>>4, then xor-reduce quarters.
    int q = f >> 4, j = f & 15;
    float s = 0.f;
    #pragma unroll
    for (int i = 0; i < 16; ++i) {
        float hk = __shfl(v, 16 * q + i);
        s = fmaf(hk, W2l[(16 * q + i) * 16 + j], s);
    }
    s += __shfl_xor(s, 16);
    s += __shfl_xor(s, 32);
    if (f < 16) Z2[node * 16 + f] = dn * s;
}

// ---- layer-2 gather: scalar lanes (16/node), pipelined tiles, 16-deep batches ----
template <int D, bool RELU>
__global__ void k_gather(const float* __restrict__ Z, const int* __restrict__ rowptr,
                         const long long* __restrict__ entq, const float* __restrict__ dis,
                         const float* __restrict__ bias, float* __restrict__ out, int N) {
    constexpr int NPB = TPB / D;
    constexpr int UN = 16;                      // outstanding neighbor rows per batch
    int node = blockIdx.x * NPB + threadIdx.x / D;
    int f = threadIdx.x % D;
    int lane = threadIdx.x & 63;
    int base = lane & ~(D - 1);
    if (node >= N) return;
    int j0 = rowptr[node], j1 = rowptr[node + 1];
    float acc = Z[node * D + f];
    long long cur = 0;
    if (j0 < j1) cur = __builtin_nontemporal_load(entq + j0 + f);  // ent padded by 64
    for (int jb = j0; jb < j1; jb += D) {
        long long nxt = cur;
        if (jb + D < j1) nxt = __builtin_nontemporal_load(entq + jb + D + f);
        int ex = (int)cur;
        float ey = __int_as_float((int)(cur >> 32));
        int cnt = j1 - jb; if (cnt > D) cnt = D;
        int k = 0;
        for (; k + UN <= cnt; k += UN) {
            int n[UN]; float w[UN], z[UN];
            #pragma unroll
            for (int u = 0; u < UN; ++u) {
                n[u] = __shfl(ex, base + k + u);
                w[u] = __shfl(ey, base + k + u);
            }
            #pragma unroll
            for (int u = 0; u < UN; ++u) z[u] = Z[n[u] * D + f];  // 16 rows in flight
            #pragma unroll
            for (int u = 0; u < UN; ++u) acc = fmaf(w[u], z[u], acc);
        }
        for (; k < cnt; ++k) {
            int n0 = __shfl(ex, base + k);
            float w0 = __shfl(ey, base + k);
            acc = fmaf(w0, Z[n0 * D + f], acc);
        }
        cur = nxt;
    }
    float v = fmaf(dis[node], acc, bias[f]);
    if (RELU) v = v > 0.f ? v : 0.f;
    out[node * D + f] = v;
}

extern "C" void kernel_launch(void* const* d_in, const int* in_sizes, int n_in,
                              void* d_out, int out_size, void* d_ws, size_t ws_size,
                              hipStream_t stream) {
    const float* x  = (const float*)d_in[0];
    const float* W1 = (const float*)d_in[1];
    const float* b1 = (const float*)d_in[2];
    const float* W2 = (const float*)d_in[3];
    const float* b2 = (const float*)d_in[4];
    const float* ew = (const float*)d_in[5];
    const int*   ei = (const int*)d_in[6];   // int32 layout (validated)

    const int N = in_sizes[0] / 64;   // 16384
    const int E = in_sizes[5];        // 524288
    const int M = 2 * E;              // CSR entries

    // bucket geometry: RN = pow2 <= 64, NBe = ceil(N/RN) <= 256
    int rsh = 0;
    while ((256 << rsh) < N) ++rsh;
    const int NBe = (N + (1 << rsh) - 1) >> rsh;
    const int GB  = (E + CHUNK - 1) / CHUNK;

    char* ws = (char*)d_ws;
    size_t off = 0;
    auto alloc = [&](size_t bytes) -> void* {
        void* p = ws + off;
        off += (bytes + 255) & ~(size_t)255;
        return p;
    };
    float* dis     = (float*)alloc((size_t)N * 4);
    int*   counts  = (int*)alloc((size_t)N * 4);          // fallback only
    int*   rowptr  = (int*)alloc(((size_t)N + 1) * 4);
    int*   cursor  = (int*)alloc((size_t)N * 4);          // fallback only
    int2*  ent     = (int2*)alloc(((size_t)M + 64) * 8);  // +64 pad: gather tile prefetch
    int*   bstartT = (int*)alloc((size_t)GB * NBe * 4);   // [k*GB + b]
    int*   bcntT   = (int*)alloc((size_t)GB * NBe * 4);   // [k*GB + b]
    int*   btot    = (int*)alloc(((size_t)NBe + 1) * 4);
    int2*  tmp     = (int2*)alloc((size_t)M * 8);         // p1 output; lower half re-used as Z1
    float* Z2      = (float*)alloc((size_t)N * 16 * 4);
    (void)ws_size; (void)n_in; (void)out_size;

    // Z1 aliases tmp's lower 4 MB: k_gemm1 writes it only AFTER k_p2 consumed tmp.
    float* Z1 = (float*)tmp;

    float* out = (float*)d_out;

    if (N <= NMAX && GB <= GBMAX) {
        k_p1<<<GB, 1024, 0, stream>>>(ei, ew, E, rsh, NBe, GB, bstartT, bcntT, tmp);
        k_colsum<<<NBe, TPB, 0, stream>>>(bcntT, GB, btot);
        k_p2<<<NBe, 1024, 0, stream>>>(tmp, bstartT, bcntT, btot, GB, rsh, N, NBe, M,
                                       ent, rowptr, dis);
    } else {
        k_init_fb<<<(N + TPB - 1) / TPB, TPB, 0, stream>>>(dis, counts, N);
        k_deg_cnt_fb<<<(E + TPB - 1) / TPB, TPB, 0, stream>>>(ei, ew, dis, counts, E);
        k_rsqrt_fb<<<(N + TPB - 1) / TPB, TPB, 0, stream>>>(dis, N);
        k_scan_fb<<<1, TPB, 0, stream>>>(counts, rowptr, cursor, N);
        k_fill_fb<<<(E + TPB - 1) / TPB, TPB, 0, stream>>>(ei, ew, cursor, ent, E);
    }

    // layer 1: gemm1 -> fused gather+gemm2 (H never leaves the CU)
    k_gemm1<<<(N + 3) / 4, TPB, 0, stream>>>(x, W1, dis, Z1, N);
    k_gather1<<<(N + 3) / 4, TPB, 0, stream>>>(Z1, rowptr, (const long long*)ent,
                                               dis, b1, W2, Z2, N);
    // layer 2
    k_gather<16, false><<<(N + 15) / 16, TPB, 0, stream>>>(Z2, rowptr, (const long long*)ent,
                                                           dis, b2, out, N);
}